// Round 1
// baseline (2475.385 us; speedup 1.0000x reference)
//
#include <hip/hip_runtime.h>
#include <cstdint>
#include <cstddef>

typedef __bf16 bf16;
typedef __bf16 bf16x8 __attribute__((ext_vector_type(8)));
typedef __bf16 bf16x4 __attribute__((ext_vector_type(4)));
typedef float f32x4 __attribute__((ext_vector_type(4)));

#define D_MODEL 1024
#define ADA_STRIDE 6144
#define ROWS_TOTAL 32768   // 8 * 4096
#define EPS_RMS 1e-5f

// ---------------------------------------------------------------------------
// Weight convert + transpose: Wt[n*K + k] = (bf16) W[k*N + n]
// K is a power of two (1024 or 4096) -> kbits. Coalesced writes, strided reads.
// ---------------------------------------------------------------------------
__global__ void wconvert_t(const float* __restrict__ W, bf16* __restrict__ Wt,
                           int kbits, int N, int total) {
  int i = blockIdx.x * 256 + threadIdx.x;
  if (i >= total) return;
  int K = 1 << kbits;
  int k = i & (K - 1);
  int n = i >> kbits;
  Wt[i] = (bf16)W[(size_t)k * N + n];
}

// ---------------------------------------------------------------------------
// ada = silu(context) @ W_ada + b_ada   (8 x 6144, K=1024) — tiny GEMM
// grid (6144/256, 8), block 256
// ---------------------------------------------------------------------------
__global__ void ada_gemm(const float* __restrict__ ctx, const float* __restrict__ W,
                         const float* __restrict__ bias, float* __restrict__ ada) {
  __shared__ float sc[D_MODEL];
  int b = blockIdx.y;
  int col = blockIdx.x * 256 + threadIdx.x;
  for (int j = threadIdx.x; j < D_MODEL; j += 256) {
    float x = ctx[b * D_MODEL + j];
    sc[j] = x / (1.f + __expf(-x));   // silu
  }
  __syncthreads();
  float acc = bias[col];
#pragma unroll 8
  for (int k = 0; k < D_MODEL; ++k)
    acc += sc[k] * W[(size_t)k * ADA_STRIDE + col];
  ada[b * ADA_STRIDE + col] = acc;
}

// ---------------------------------------------------------------------------
// Fused RMSNorm + adaLN modulation, fp32 in -> bf16 out.
// out = rmsnorm(x)*scale * (1 + ada[scOff]) + ada[shOff]
// grid ROWS_TOTAL, block 256 (4 elems/thread)
// ---------------------------------------------------------------------------
__global__ void rmsnorm_mod(const float* __restrict__ x, const float* __restrict__ scale,
                            const float* __restrict__ ada, int shOff, int scOff,
                            bf16* __restrict__ out) {
  int row = blockIdx.x;
  int b = row >> 12;           // 4096 rows per batch
  int t = threadIdx.x;
  const float* xr = x + (size_t)row * D_MODEL;
  float4 v = ((const float4*)xr)[t];
  float ss = v.x * v.x + v.y * v.y + v.z * v.z + v.w * v.w;
#pragma unroll
  for (int m = 32; m >= 1; m >>= 1) ss += __shfl_xor(ss, m, 64);
  __shared__ float ws[4];
  if ((t & 63) == 0) ws[t >> 6] = ss;
  __syncthreads();
  float tot = ws[0] + ws[1] + ws[2] + ws[3];
  float rms = rsqrtf(tot * (1.f / D_MODEL) + EPS_RMS);
  const float* ab = ada + b * ADA_STRIDE;
  int d0 = t * 4;
  float vv[4] = {v.x, v.y, v.z, v.w};
  bf16x4 o4;
#pragma unroll
  for (int j = 0; j < 4; ++j) {
    int d = d0 + j;
    float y = vv[j] * rms * scale[d];
    y = y * (1.f + ab[scOff + d]) + ab[shOff + d];
    o4[j] = (bf16)y;
  }
  *(bf16x4*)(out + (size_t)row * D_MODEL + d0) = o4;
}

// ---------------------------------------------------------------------------
// MFMA bf16 GEMM: C[M,N] = A[M,K] @ Bt[N,K]^T + bias, 128x128 tile, BK=32.
// 256 threads = 4 waves in 2x2; each wave 64x64 = 4x4 mfma_16x16x32 tiles.
// Verified fragment mappings (learn_hip m89/m90): A/B lane holds [m|n=lane&15]
// [k=(lane>>4)*8+j] (16B contiguous); C/D: col=lane&15, row=(lane>>4)*4+reg.
// EPI: 0 = bf16 store (+bias), 1 = gelu-tanh -> bf16,
//      2 = outF = resid + ada[gOff]*(v)   (residual + gate, fp32)
//      3 = outF += ada[gOff]*(v)          (accumulate into existing fp32)
// ---------------------------------------------------------------------------
template <int EPI>
__global__ __launch_bounds__(256) void gemm128(
    const bf16* __restrict__ A, const bf16* __restrict__ Bt,
    const float* __restrict__ bias, int K, int N,
    bf16* __restrict__ outB, float* __restrict__ outF,
    const float* __restrict__ resid, const float* __restrict__ ada, int gOff) {
  __shared__ bf16 sA[128 * 32];
  __shared__ bf16 sB[128 * 32];
  const int tid = threadIdx.x;
  const int lane = tid & 63;
  const int wv = tid >> 6;
  const int wr = (wv >> 1) * 64;
  const int wc = (wv & 1) * 64;
  const int lm = lane & 15;
  const int lq = lane >> 4;
  const int tileM = blockIdx.x * 128;
  const int tileN = blockIdx.y * 128;
  const int aRow = tid >> 2;            // 0..63
  const int aCol = (tid & 3) * 8;       // 0,8,16,24

  f32x4 acc[4][4];
#pragma unroll
  for (int i = 0; i < 4; ++i)
#pragma unroll
    for (int j = 0; j < 4; ++j) acc[i][j] = (f32x4){0.f, 0.f, 0.f, 0.f};

  for (int kk = 0; kk < K; kk += 32) {
    uint4 a0 = *(const uint4*)(A + (size_t)(tileM + aRow) * K + kk + aCol);
    uint4 a1 = *(const uint4*)(A + (size_t)(tileM + aRow + 64) * K + kk + aCol);
    uint4 b0 = *(const uint4*)(Bt + (size_t)(tileN + aRow) * K + kk + aCol);
    uint4 b1 = *(const uint4*)(Bt + (size_t)(tileN + aRow + 64) * K + kk + aCol);
    __syncthreads();
    *(uint4*)(sA + aRow * 32 + aCol) = a0;
    *(uint4*)(sA + (aRow + 64) * 32 + aCol) = a1;
    *(uint4*)(sB + aRow * 32 + aCol) = b0;
    *(uint4*)(sB + (aRow + 64) * 32 + aCol) = b1;
    __syncthreads();
    bf16x8 af[4], bfr[4];
#pragma unroll
    for (int mi = 0; mi < 4; ++mi)
      af[mi] = *(const bf16x8*)(sA + (wr + mi * 16 + lm) * 32 + lq * 8);
#pragma unroll
    for (int ni = 0; ni < 4; ++ni)
      bfr[ni] = *(const bf16x8*)(sB + (wc + ni * 16 + lm) * 32 + lq * 8);
#pragma unroll
    for (int mi = 0; mi < 4; ++mi)
#pragma unroll
      for (int ni = 0; ni < 4; ++ni)
        acc[mi][ni] = __builtin_amdgcn_mfma_f32_16x16x32_bf16(af[mi], bfr[ni], acc[mi][ni], 0, 0, 0);
  }

#pragma unroll
  for (int mi = 0; mi < 4; ++mi) {
    int row0 = tileM + wr + mi * 16 + lq * 4;
#pragma unroll
    for (int ni = 0; ni < 4; ++ni) {
      int col = tileN + wc + ni * 16 + lm;
      float bs = bias[col];
#pragma unroll
      for (int r = 0; r < 4; ++r) {
        int row = row0 + r;
        float v = acc[mi][ni][r] + bs;
        size_t idx = (size_t)row * N + col;
        if (EPI == 0) {
          outB[idx] = (bf16)v;
        } else if (EPI == 1) {
          float g = 0.5f * v * (1.f + tanhf(0.7978845608028654f * (v + 0.044715f * v * v * v)));
          outB[idx] = (bf16)g;
        } else if (EPI == 2) {
          int b = row >> 12;
          float g = ada[b * ADA_STRIDE + gOff + col];
          outF[idx] = resid[idx] + g * v;
        } else {
          int b = row >> 12;
          float g = ada[b * ADA_STRIDE + gOff + col];
          outF[idx] = outF[idx] + g * v;
        }
      }
    }
  }
}

// ---------------------------------------------------------------------------
// Windowed attention, one block per (window, head). 2048 blocks, 256 threads.
// qkv rows: token*3072, q at h*128, k at 1024+h*128, v at 2048+h*128.
// RoPE applied on LDS load (reference repeat-style: pair (p, p+64),
// freq_lo = 10000^-(p/2)/64, freq_hi = freq_lo * 0.01).
// LDS: sK 128x136 (pad 8 bf16 keeps 16B align, breaks bank aliasing),
//      sV 128x128, sQ 16x128 chunk, sS 16x128 fp32 P-matrix. 79872 B dynamic.
// ---------------------------------------------------------------------------
#define ATTN_LDS (128 * 136 * 2 + 128 * 128 * 2 + 16 * 128 * 2 + 16 * 128 * 4)

__global__ __launch_bounds__(256) void attn_kernel(const bf16* __restrict__ qkv,
                                                   bf16* __restrict__ o) {
  extern __shared__ char smem[];
  bf16* sK = (bf16*)smem;                 // 128 x 136
  bf16* sV = sK + 128 * 136;              // 128 x 128
  bf16* sQ = sV + 128 * 128;              // 16 x 128
  float* sS = (float*)(sQ + 16 * 128);    // 16 x 128
  const int tid = threadIdx.x;
  const int w = blockIdx.x >> 3;
  const int h = blockIdx.x & 7;
  const size_t base = (size_t)w * 128 * 3072 + h * 128;

  // load K (raw) and V
  for (int i = tid; i < 2048; i += 256) {
    int r = i >> 4, c = (i & 15) * 8;
    *(uint4*)(sK + r * 136 + c) = *(const uint4*)(qkv + base + (size_t)r * 3072 + 1024 + c);
    *(uint4*)(sV + r * 128 + c) = *(const uint4*)(qkv + base + (size_t)r * 3072 + 2048 + c);
  }
  __syncthreads();
  // rope K in place: 128 rows x 64 pairs
  for (int i = tid; i < 8192; i += 256) {
    int r = i >> 6, p = i & 63;
    float xl = (float)sK[r * 136 + p];
    float xh = (float)sK[r * 136 + p + 64];
    float fl = __expf((float)(p >> 1) * -0.14391156831f);  // ln(10000)/64
    float al = (float)r * fl;
    float ah = al * 0.01f;  // 10000^(-32/64) = 0.01
    sK[r * 136 + p]      = (bf16)(xl * cosf(al) - xh * sinf(al));
    sK[r * 136 + p + 64] = (bf16)(xh * cosf(ah) + xl * sinf(ah));
  }
  __syncthreads();

  const int qi = tid >> 4;   // 0..15 query within chunk
  const int kg = tid & 15;   // 0..15 key group / d group

  for (int qc = 0; qc < 8; ++qc) {
    // load + rope Q chunk (16 rows)
    for (int i = tid; i < 1024; i += 256) {
      int r = i >> 6, p = i & 63;
      int grow = qc * 16 + r;
      float xl = (float)qkv[base + (size_t)grow * 3072 + p];
      float xh = (float)qkv[base + (size_t)grow * 3072 + p + 64];
      float fl = __expf((float)(p >> 1) * -0.14391156831f);
      float al = (float)grow * fl;
      float ah = al * 0.01f;
      sQ[r * 128 + p]      = (bf16)(xl * cosf(al) - xh * sinf(al));
      sQ[r * 128 + p + 64] = (bf16)(xh * cosf(ah) + xl * sinf(ah));
    }
    __syncthreads();

    // S = Q K^T : thread handles query qi, keys kg + 16j
    float accS[8];
#pragma unroll
    for (int j = 0; j < 8; ++j) accS[j] = 0.f;
    for (int d8 = 0; d8 < 16; ++d8) {
      bf16x8 qv = *(const bf16x8*)(sQ + qi * 128 + d8 * 8);
      float qf[8];
#pragma unroll
      for (int i = 0; i < 8; ++i) qf[i] = (float)qv[i];
#pragma unroll
      for (int j = 0; j < 8; ++j) {
        int key = kg + j * 16;
        bf16x8 kv = *(const bf16x8*)(sK + key * 136 + d8 * 8);
        float s = 0.f;
#pragma unroll
        for (int i = 0; i < 8; ++i) s += qf[i] * (float)kv[i];
        accS[j] += s;
      }
    }
    // softmax across the row's 16 lanes (masks 1,2,4,8 stay in-group)
    const float sc = 0.08838834764831845f;  // 1/sqrt(128)
    float mx = -1e30f;
#pragma unroll
    for (int j = 0; j < 8; ++j) { accS[j] *= sc; mx = fmaxf(mx, accS[j]); }
#pragma unroll
    for (int m = 1; m < 16; m <<= 1) mx = fmaxf(mx, __shfl_xor(mx, m, 64));
    float sum = 0.f;
#pragma unroll
    for (int j = 0; j < 8; ++j) { accS[j] = __expf(accS[j] - mx); sum += accS[j]; }
#pragma unroll
    for (int m = 1; m < 16; m <<= 1) sum += __shfl_xor(sum, m, 64);
    float inv = 1.f / sum;
#pragma unroll
    for (int j = 0; j < 8; ++j) sS[qi * 128 + kg + j * 16] = accS[j] * inv;
    __syncthreads();

    // O = P V : thread handles query qi, dims kg*8..+8
    float accO[8];
#pragma unroll
    for (int i = 0; i < 8; ++i) accO[i] = 0.f;
    for (int k = 0; k < 128; ++k) {
      float p = sS[qi * 128 + k];
      bf16x8 vv = *(const bf16x8*)(sV + k * 128 + kg * 8);
#pragma unroll
      for (int i = 0; i < 8; ++i) accO[i] += p * (float)vv[i];
    }
    bf16x8 ov;
#pragma unroll
    for (int i = 0; i < 8; ++i) ov[i] = (bf16)accO[i];
    *(bf16x8*)(o + (size_t)(w * 128 + qc * 16 + qi) * 1024 + h * 128 + kg * 8) = ov;
    __syncthreads();  // protect sQ/sS before next chunk
  }
}

// ---------------------------------------------------------------------------
extern "C" void kernel_launch(void* const* d_in, const int* in_sizes, int n_in,
                              void* d_out, int out_size, void* d_ws, size_t ws_size,
                              hipStream_t stream) {
  const float* group_x = (const float*)d_in[0];
  const float* context = (const float*)d_in[1];
  const float* W_ada   = (const float*)d_in[2];
  const float* b_ada   = (const float*)d_in[3];
  const float* scale1  = (const float*)d_in[4];
  const float* W_qkv   = (const float*)d_in[5];
  const float* b_qkv   = (const float*)d_in[6];
  const float* W_out   = (const float*)d_in[7];
  const float* b_out   = (const float*)d_in[8];
  const float* scale2  = (const float*)d_in[9];
  const float* W_ff1   = (const float*)d_in[10];
  const float* b_ff1   = (const float*)d_in[11];
  const float* W_ff2   = (const float*)d_in[12];
  const float* b_ff2   = (const float*)d_in[13];
  float* out = (float*)d_out;

  // workspace layout (total ~345 MiB)
  char* ws = (char*)d_ws;
  float* ada   = (float*)ws;                         // 8*6144*4 = 196608
  bf16* wqkv_t = (bf16*)(ws + 196608);               // 3072x1024
  bf16* wout_t = wqkv_t + (size_t)3072 * 1024;       // 1024x1024
  bf16* wff1_t = wout_t + (size_t)1024 * 1024;       // 4096x1024
  bf16* wff2_t = wff1_t + (size_t)4096 * 1024;       // 1024x4096
  bf16* bufX   = wff2_t + (size_t)1024 * 4096;       // 32768x1024 (xmod -> o -> hmod)
  bf16* bufBig = bufX + (size_t)ROWS_TOTAL * 1024;   // qkv (32768x3072) then h1 (32768x4096)

  // 0) weight convert+transpose -> bf16 N x K
  wconvert_t<<<dim3(3072 * 1024 / 256), 256, 0, stream>>>(W_qkv, wqkv_t, 10, 3072, 3072 * 1024);
  wconvert_t<<<dim3(1024 * 1024 / 256), 256, 0, stream>>>(W_out, wout_t, 10, 1024, 1024 * 1024);
  wconvert_t<<<dim3(4096 * 1024 / 256), 256, 0, stream>>>(W_ff1, wff1_t, 10, 4096, 4096 * 1024);
  wconvert_t<<<dim3(1024 * 4096 / 256), 256, 0, stream>>>(W_ff2, wff2_t, 12, 1024, 1024 * 4096);

  // 1) ada = silu(context) @ W_ada + b_ada
  ada_gemm<<<dim3(ADA_STRIDE / 256, 8), 256, 0, stream>>>(context, W_ada, b_ada, ada);

  // 2) xmod = rmsnorm(group_x)*scale1 * (1+sc_msa) + sh_msa  (bf16)
  rmsnorm_mod<<<ROWS_TOTAL, 256, 0, stream>>>(group_x, scale1, ada, 0, 1024, bufX);

  // 3) qkv = xmod @ W_qkv + b_qkv  (bf16)
  gemm128<0><<<dim3(ROWS_TOTAL / 128, 3072 / 128), 256, 0, stream>>>(
      bufX, wqkv_t, b_qkv, 1024, 3072, bufBig, nullptr, nullptr, nullptr, 0);

  // 4) windowed attention (rope fused) -> o (bf16, reuses bufX)
  static bool attn_attr_set = false;
  hipFuncSetAttribute(reinterpret_cast<const void*>(&attn_kernel),
                      hipFuncAttributeMaxDynamicSharedMemorySize, ATTN_LDS);
  (void)attn_attr_set;
  attn_kernel<<<dim3(256 * 8), 256, ATTN_LDS, stream>>>(bufBig, bufX);

  // 5) res2 = group_x + g_msa * (o @ W_out + b_out)  -> d_out (fp32)
  gemm128<2><<<dim3(ROWS_TOTAL / 128, 1024 / 128), 256, 0, stream>>>(
      bufX, wout_t, b_out, 1024, 1024, nullptr, out, group_x, ada, 2048);

  // 6) hmod = rmsnorm(res2)*scale2 * (1+sc_mlp) + sh_mlp  (bf16, reuses bufX)
  rmsnorm_mod<<<ROWS_TOTAL, 256, 0, stream>>>(out, scale2, ada, 3072, 4096, bufX);

  // 7) h1 = gelu(hmod @ W_ff1 + b_ff1)  (bf16, reuses bufBig)
  gemm128<1><<<dim3(ROWS_TOTAL / 128, 4096 / 128), 256, 0, stream>>>(
      bufX, wff1_t, b_ff1, 1024, 4096, bufBig, nullptr, nullptr, nullptr, 0);

  // 8) d_out = res2 + g_mlp * (h1 @ W_ff2 + b_ff2)
  gemm128<3><<<dim3(ROWS_TOTAL / 128, 1024 / 128), 256, 0, stream>>>(
      bufBig, wff2_t, b_ff2, 4096, 1024, nullptr, out, nullptr, ada, 5120);
}

// Round 2
// 2112.900 us; speedup vs baseline: 1.1716x; 1.1716x over previous
//
#include <hip/hip_runtime.h>
#include <cstdint>
#include <cstddef>

typedef __bf16 bf16;
typedef __bf16 bf16x2 __attribute__((ext_vector_type(2)));
typedef __bf16 bf16x4 __attribute__((ext_vector_type(4)));
typedef __bf16 bf16x8 __attribute__((ext_vector_type(8)));
typedef float f32x4 __attribute__((ext_vector_type(4)));

#define D_MODEL 1024
#define ADA_STRIDE 6144
#define ROWS_TOTAL 32768   // 8 * 4096
#define EPS_RMS 1e-5f

// async global->LDS, 16B per lane; LDS dest must be wave-uniform base + lane*16
__device__ __forceinline__ void gld16(const void* g, void* l) {
  __builtin_amdgcn_global_load_lds((const __attribute__((address_space(1))) void*)g,
                                   (__attribute__((address_space(3))) void*)l, 16, 0, 0);
}

// ---------------------------------------------------------------------------
// Weight convert + transpose: Wt[n*K + k] = (bf16) W[k*N + n]
// ---------------------------------------------------------------------------
__global__ void wconvert_t(const float* __restrict__ W, bf16* __restrict__ Wt,
                           int kbits, int N, int total) {
  int i = blockIdx.x * 256 + threadIdx.x;
  if (i >= total) return;
  int K = 1 << kbits;
  int k = i & (K - 1);
  int n = i >> kbits;
  Wt[i] = (bf16)W[(size_t)k * N + n];
}

// ---------------------------------------------------------------------------
// ada = silu(context) @ W_ada + b_ada   (8 x 6144, K=1024)
// ---------------------------------------------------------------------------
__global__ void ada_gemm(const float* __restrict__ ctx, const float* __restrict__ W,
                         const float* __restrict__ bias, float* __restrict__ ada) {
  __shared__ float sc[D_MODEL];
  int b = blockIdx.y;
  int col = blockIdx.x * 256 + threadIdx.x;
  for (int j = threadIdx.x; j < D_MODEL; j += 256) {
    float x = ctx[b * D_MODEL + j];
    sc[j] = x / (1.f + __expf(-x));
  }
  __syncthreads();
  float acc = bias[col];
#pragma unroll 8
  for (int k = 0; k < D_MODEL; ++k)
    acc += sc[k] * W[(size_t)k * ADA_STRIDE + col];
  ada[b * ADA_STRIDE + col] = acc;
}

// ---------------------------------------------------------------------------
// Fused RMSNorm + adaLN modulation, fp32 in -> bf16 out.
// ---------------------------------------------------------------------------
__global__ void rmsnorm_mod(const float* __restrict__ x, const float* __restrict__ scale,
                            const float* __restrict__ ada, int shOff, int scOff,
                            bf16* __restrict__ out) {
  int row = blockIdx.x;
  int b = row >> 12;
  int t = threadIdx.x;
  const float* xr = x + (size_t)row * D_MODEL;
  float4 v = ((const float4*)xr)[t];
  float ss = v.x * v.x + v.y * v.y + v.z * v.z + v.w * v.w;
#pragma unroll
  for (int m = 32; m >= 1; m >>= 1) ss += __shfl_xor(ss, m, 64);
  __shared__ float ws[4];
  if ((t & 63) == 0) ws[t >> 6] = ss;
  __syncthreads();
  float tot = ws[0] + ws[1] + ws[2] + ws[3];
  float rms = rsqrtf(tot * (1.f / D_MODEL) + EPS_RMS);
  const float* ab = ada + b * ADA_STRIDE;
  int d0 = t * 4;
  float vv[4] = {v.x, v.y, v.z, v.w};
  bf16x4 o4;
#pragma unroll
  for (int j = 0; j < 4; ++j) {
    int d = d0 + j;
    float y = vv[j] * rms * scale[d];
    y = y * (1.f + ab[scOff + d]) + ab[shOff + d];
    o4[j] = (bf16)y;
  }
  *(bf16x4*)(out + (size_t)row * D_MODEL + d0) = o4;
}

// ---------------------------------------------------------------------------
// RoPE in place on qkvQK [32768][2048]: q heads (cols 0..1023), k (1024..2047).
// thread = (token, pair-of-pairs i): d in {2i,2i+1} share angle; {64+2i,64+2i+1}
// share the 0.01x angle. One sincos pair per thread, applied to 16 head-blocks.
// ---------------------------------------------------------------------------
__global__ void rope_kernel(bf16* __restrict__ qk) {
  int gid = blockIdx.x * 256 + threadIdx.x;   // 32768 * 32
  int t = gid >> 5, i = gid & 31;
  int pos = t & 127;
  float fl = __expf((float)i * -0.14391156831f);   // 10000^(-i/64)
  float al = (float)pos * fl, ah = al * 0.01f;
  float sl, cl, sh, ch;
  __sincosf(al, &sl, &cl);
  __sincosf(ah, &sh, &ch);
  bf16* row = qk + (size_t)t * 2048;
  int d0 = i * 2;
#pragma unroll
  for (int h8 = 0; h8 < 16; ++h8) {
    bf16* hp = row + h8 * 128;
    bf16x2 lo = *(bf16x2*)(hp + d0);
    bf16x2 hi = *(bf16x2*)(hp + 64 + d0);
    bf16x2 olo, ohi;
#pragma unroll
    for (int j = 0; j < 2; ++j) {
      float xl = (float)lo[j], xh = (float)hi[j];
      olo[j] = (bf16)(xl * cl - xh * sl);
      ohi[j] = (bf16)(xh * ch + xl * sh);
    }
    *(bf16x2*)(hp + d0) = olo;
    *(bf16x2*)(hp + 64 + d0) = ohi;
  }
}

// ---------------------------------------------------------------------------
// MFMA bf16 GEMM with global_load_lds staging (m97 structure).
// C[M,N] = A[M,K] @ Bt[N,K]^T + bias, 128x128 tile, BK=32.
// EPI: 0 = bf16 store (+bias[col]), 1 = gelu -> bf16,
//      2 = outF = resid + ada[gOff+col]*v, 3 = outF += ada[gOff+col]*v,
//      4 = bf16 store (+bias[row])  [for the V^T gemm]
// ---------------------------------------------------------------------------
template <int EPI>
__global__ __launch_bounds__(256) void gemm128(
    const bf16* __restrict__ A, const bf16* __restrict__ Bt,
    const float* __restrict__ bias, int K, int N,
    bf16* __restrict__ outB, float* __restrict__ outF,
    const float* __restrict__ resid, const float* __restrict__ ada, int gOff) {
  __shared__ bf16 sA[128 * 32];
  __shared__ bf16 sB[128 * 32];
  const int tid = threadIdx.x;
  const int lane = tid & 63;
  const int wv = tid >> 6;
  const int wr = (wv >> 1) * 64;
  const int wc = (wv & 1) * 64;
  const int lm = lane & 15;
  const int lq = lane >> 4;
  const int tileM = blockIdx.x * 128;
  const int tileN = blockIdx.y * 128;
  const int sRow = tid >> 2;
  const int sCol = (tid & 3) * 8;
  const bf16* gA = A + (size_t)(tileM + sRow) * K + sCol;
  const bf16* gB = Bt + (size_t)(tileN + sRow) * K + sCol;
  bf16* lA = sA + tid * 8;
  bf16* lB = sB + tid * 8;

  f32x4 acc[4][4];
#pragma unroll
  for (int i = 0; i < 4; ++i)
#pragma unroll
    for (int j = 0; j < 4; ++j) acc[i][j] = (f32x4){0.f, 0.f, 0.f, 0.f};

  for (int kk = 0; kk < K; kk += 32) {
    __syncthreads();
    gld16(gA + kk, lA);
    gld16(gA + kk + (size_t)64 * K, lA + 64 * 32);
    gld16(gB + kk, lB);
    gld16(gB + kk + (size_t)64 * K, lB + 64 * 32);
    __syncthreads();
    bf16x8 af[4], bfr[4];
#pragma unroll
    for (int mi = 0; mi < 4; ++mi)
      af[mi] = *(const bf16x8*)(sA + (wr + mi * 16 + lm) * 32 + lq * 8);
#pragma unroll
    for (int ni = 0; ni < 4; ++ni)
      bfr[ni] = *(const bf16x8*)(sB + (wc + ni * 16 + lm) * 32 + lq * 8);
#pragma unroll
    for (int mi = 0; mi < 4; ++mi)
#pragma unroll
      for (int ni = 0; ni < 4; ++ni)
        acc[mi][ni] = __builtin_amdgcn_mfma_f32_16x16x32_bf16(af[mi], bfr[ni], acc[mi][ni], 0, 0, 0);
  }

#pragma unroll
  for (int mi = 0; mi < 4; ++mi) {
    int row0 = tileM + wr + mi * 16 + lq * 4;
#pragma unroll
    for (int ni = 0; ni < 4; ++ni) {
      int col = tileN + wc + ni * 16 + lm;
      float bc = (EPI == 4) ? 0.f : bias[col];
#pragma unroll
      for (int r = 0; r < 4; ++r) {
        int row = row0 + r;
        float v = acc[mi][ni][r] + ((EPI == 4) ? bias[row] : bc);
        size_t idx = (size_t)row * N + col;
        if (EPI == 0 || EPI == 4) {
          outB[idx] = (bf16)v;
        } else if (EPI == 1) {
          // exact tanh-gelu via sigmoid: 0.5(1+tanh(s)) = sigmoid(2s)
          float s2 = 1.5957691216057308f * (v + 0.044715f * v * v * v);
          outB[idx] = (bf16)(v / (1.f + __expf(-s2)));
        } else if (EPI == 2) {
          int b = row >> 12;
          float g = ada[b * ADA_STRIDE + gOff + col];
          outF[idx] = resid[idx] + g * v;
        } else {
          int b = row >> 12;
          float g = ada[b * ADA_STRIDE + gOff + col];
          outF[idx] = outF[idx] + g * v;
        }
      }
    }
  }
}

// ---------------------------------------------------------------------------
// MFMA windowed attention. Block = (window, head), 4 waves x 32 queries.
// qk: roped [32768][2048] (q at h*128, k at 1024+h*128); vt: [1024][32768].
// LDS: two 32KB swizzled buffers (group g of row r stored at g^(r&15)):
//   qbuf = Q, later P;  kbuf = K, later V^T rows.
// S^T = K@Q^T via mfma(A=K,B=Q): C col = q (lane&15), row = key (quad*4+reg)
// -> softmax = 32 in-lane values + shfl_xor(16,32). P written as bf16x4 runs.
// O = P@V^T via mfma(A=P,B=Vt). All staging via global_load_lds (swizzle on
// the global-address side since GLD's LDS dest is fixed base+lane*16).
// ---------------------------------------------------------------------------
#define ATTN_LDS 65536

__global__ __launch_bounds__(256, 2) void attn_kernel(
    const bf16* __restrict__ qk, const bf16* __restrict__ vt, bf16* __restrict__ o) {
  extern __shared__ char smem[];
  bf16* qbuf = (bf16*)smem;            // 128x128 swizzled (Q -> P)
  bf16* kbuf = qbuf + 128 * 128;       // 128x128 swizzled (K -> Vt)
  const int tid = threadIdx.x;
  const int lane = tid & 63;
  const int wv = tid >> 6;
  const int lm = lane & 15;
  const int quad = lane >> 4;
  const int w = blockIdx.x >> 3;
  const int h = blockIdx.x & 7;
  const int wbase = w * 128;

  // stage Q and K (swizzled via global source addresses)
#pragma unroll
  for (int it = 0; it < 8; ++it) {
    int c = it * 256 + tid;
    int r = c >> 4, gst = c & 15;
    int goff = (gst ^ (r & 15)) * 8;
    const bf16* rowp = qk + (size_t)(wbase + r) * 2048 + h * 128 + goff;
    gld16(rowp, qbuf + c * 8);
    gld16(rowp + 1024, kbuf + c * 8);
  }
  __syncthreads();

  const int wq0 = wv * 32;
  f32x4 accS[8][2];
#pragma unroll
  for (int mi = 0; mi < 8; ++mi)
#pragma unroll
    for (int ni = 0; ni < 2; ++ni) accS[mi][ni] = (f32x4){0.f, 0.f, 0.f, 0.f};

#pragma unroll
  for (int s = 0; s < 4; ++s) {
    bf16x8 bq[2], ak[8];
#pragma unroll
    for (int ni = 0; ni < 2; ++ni)
      bq[ni] = *(const bf16x8*)(qbuf + (wq0 + ni * 16 + lm) * 128 + ((s * 4 + quad) ^ lm) * 8);
#pragma unroll
    for (int mi = 0; mi < 8; ++mi)
      ak[mi] = *(const bf16x8*)(kbuf + (mi * 16 + lm) * 128 + ((s * 4 + quad) ^ lm) * 8);
#pragma unroll
    for (int mi = 0; mi < 8; ++mi)
#pragma unroll
      for (int ni = 0; ni < 2; ++ni)
        accS[mi][ni] = __builtin_amdgcn_mfma_f32_16x16x32_bf16(ak[mi], bq[ni], accS[mi][ni], 0, 0, 0);
  }

  // softmax over key (rows of S^T): per lane 2 q's, 32 in-lane + cross-quad
  const float scl = 0.08838834764831845f;  // 1/sqrt(128)
  float mx[2] = {-1e30f, -1e30f}, sm[2] = {0.f, 0.f};
#pragma unroll
  for (int mi = 0; mi < 8; ++mi)
#pragma unroll
    for (int ni = 0; ni < 2; ++ni)
#pragma unroll
      for (int r = 0; r < 4; ++r) {
        accS[mi][ni][r] *= scl;
        mx[ni] = fmaxf(mx[ni], accS[mi][ni][r]);
      }
#pragma unroll
  for (int ni = 0; ni < 2; ++ni) {
    mx[ni] = fmaxf(mx[ni], __shfl_xor(mx[ni], 16, 64));
    mx[ni] = fmaxf(mx[ni], __shfl_xor(mx[ni], 32, 64));
  }
#pragma unroll
  for (int mi = 0; mi < 8; ++mi)
#pragma unroll
    for (int ni = 0; ni < 2; ++ni)
#pragma unroll
      for (int r = 0; r < 4; ++r) {
        accS[mi][ni][r] = __expf(accS[mi][ni][r] - mx[ni]);
        sm[ni] += accS[mi][ni][r];
      }
#pragma unroll
  for (int ni = 0; ni < 2; ++ni) {
    sm[ni] += __shfl_xor(sm[ni], 16, 64);
    sm[ni] += __shfl_xor(sm[ni], 32, 64);
    sm[ni] = 1.f / sm[ni];
  }
  __syncthreads();  // all waves done reading Q,K from LDS

  // write P (bf16) into qbuf; start async V^T load into kbuf
#pragma unroll
  for (int mi = 0; mi < 8; ++mi)
#pragma unroll
    for (int ni = 0; ni < 2; ++ni) {
      int q = wq0 + ni * 16 + lm;
      int gst = (mi * 2 + (quad >> 1)) ^ lm;
      bf16x4 pk;
#pragma unroll
      for (int r = 0; r < 4; ++r) pk[r] = (bf16)(accS[mi][ni][r] * sm[ni]);
      *(bf16x4*)(qbuf + q * 128 + gst * 8 + (quad & 1) * 4) = pk;
    }
#pragma unroll
  for (int it = 0; it < 8; ++it) {
    int c = it * 256 + tid;
    int r = c >> 4, gst = c & 15;
    gld16(vt + (size_t)(h * 128 + r) * 32768 + wbase + (gst ^ (r & 15)) * 8, kbuf + c * 8);
  }
  __syncthreads();

  // O = P @ V^T
  f32x4 accO[2][8];
#pragma unroll
  for (int mi = 0; mi < 2; ++mi)
#pragma unroll
    for (int ni = 0; ni < 8; ++ni) accO[mi][ni] = (f32x4){0.f, 0.f, 0.f, 0.f};
#pragma unroll
  for (int s = 0; s < 4; ++s) {
    bf16x8 ap[2], bv[8];
#pragma unroll
    for (int mi = 0; mi < 2; ++mi)
      ap[mi] = *(const bf16x8*)(qbuf + (wq0 + mi * 16 + lm) * 128 + ((s * 4 + quad) ^ lm) * 8);
#pragma unroll
    for (int ni = 0; ni < 8; ++ni)
      bv[ni] = *(const bf16x8*)(kbuf + (ni * 16 + lm) * 128 + ((s * 4 + quad) ^ lm) * 8);
#pragma unroll
    for (int mi = 0; mi < 2; ++mi)
#pragma unroll
      for (int ni = 0; ni < 8; ++ni)
        accO[mi][ni] = __builtin_amdgcn_mfma_f32_16x16x32_bf16(ap[mi], bv[ni], accO[mi][ni], 0, 0, 0);
  }

  // store O: row = q (quad*4+reg), col = d (lane&15)
#pragma unroll
  for (int mi = 0; mi < 2; ++mi)
#pragma unroll
    for (int ni = 0; ni < 8; ++ni) {
      int d = ni * 16 + lm;
#pragma unroll
      for (int r = 0; r < 4; ++r) {
        int q = wq0 + mi * 16 + quad * 4 + r;
        o[(size_t)(wbase + q) * 1024 + h * 128 + d] = (bf16)accO[mi][ni][r];
      }
    }
}

// ---------------------------------------------------------------------------
extern "C" void kernel_launch(void* const* d_in, const int* in_sizes, int n_in,
                              void* d_out, int out_size, void* d_ws, size_t ws_size,
                              hipStream_t stream) {
  const float* group_x = (const float*)d_in[0];
  const float* context = (const float*)d_in[1];
  const float* W_ada   = (const float*)d_in[2];
  const float* b_ada   = (const float*)d_in[3];
  const float* scale1  = (const float*)d_in[4];
  const float* W_qkv   = (const float*)d_in[5];
  const float* b_qkv   = (const float*)d_in[6];
  const float* W_out   = (const float*)d_in[7];
  const float* b_out   = (const float*)d_in[8];
  const float* scale2  = (const float*)d_in[9];
  const float* W_ff1   = (const float*)d_in[10];
  const float* b_ff1   = (const float*)d_in[11];
  const float* W_ff2   = (const float*)d_in[12];
  const float* b_ff2   = (const float*)d_in[13];
  float* out = (float*)d_out;

  // workspace layout (peak ~344 MiB, same as round 1):
  char* ws = (char*)d_ws;
  float* ada   = (float*)ws;                          // 196,608 B
  bf16* wqkv_t = (bf16*)(ws + 196608);                // 3072x1024 (rows 2048.. are Wv^T)
  bf16* wout_t = wqkv_t + (size_t)3072 * 1024;        // 1024x1024
  bf16* wff1_t = wout_t + (size_t)1024 * 1024;        // 4096x1024
  bf16* wff2_t = wff1_t + (size_t)4096 * 1024;        // 1024x4096
  bf16* bufX   = wff2_t + (size_t)1024 * 4096;        // 32768x1024 (xmod -> o -> hmod)
  bf16* qkvQK  = bufX + (size_t)ROWS_TOTAL * 1024;    // 32768x2048 (roped in place)
  bf16* vtbuf  = qkvQK + (size_t)ROWS_TOTAL * 2048;   // 1024x32768
  bf16* h1     = qkvQK;                               // 32768x4096 aliases qkvQK+vtbuf (+55MB)

  // 0) weight convert+transpose
  wconvert_t<<<dim3(3072 * 1024 / 256), 256, 0, stream>>>(W_qkv, wqkv_t, 10, 3072, 3072 * 1024);
  wconvert_t<<<dim3(1024 * 1024 / 256), 256, 0, stream>>>(W_out, wout_t, 10, 1024, 1024 * 1024);
  wconvert_t<<<dim3(4096 * 1024 / 256), 256, 0, stream>>>(W_ff1, wff1_t, 10, 4096, 4096 * 1024);
  wconvert_t<<<dim3(1024 * 4096 / 256), 256, 0, stream>>>(W_ff2, wff2_t, 12, 1024, 1024 * 4096);

  // 1) ada
  ada_gemm<<<dim3(ADA_STRIDE / 256, 8), 256, 0, stream>>>(context, W_ada, b_ada, ada);

  // 2) xmod
  rmsnorm_mod<<<ROWS_TOTAL, 256, 0, stream>>>(group_x, scale1, ada, 0, 1024, bufX);

  // 3a) qk = xmod @ W_qk + b   (N=2048)
  gemm128<0><<<dim3(ROWS_TOTAL / 128, 2048 / 128), 256, 0, stream>>>(
      bufX, wqkv_t, b_qkv, 1024, 2048, qkvQK, nullptr, nullptr, nullptr, 0);

  // 3b) vT[vfeat][token] = Wv^T @ xmod^T + b_v[row]  (M=1024, N=32768)
  gemm128<4><<<dim3(1024 / 128, ROWS_TOTAL / 128), 256, 0, stream>>>(
      wqkv_t + (size_t)2048 * 1024, bufX, b_qkv + 2048, 1024, ROWS_TOTAL,
      vtbuf, nullptr, nullptr, nullptr, 0);

  // 3c) rope q,k in place
  rope_kernel<<<dim3(ROWS_TOTAL * 32 / 256), 256, 0, stream>>>(qkvQK);

  // 4) attention -> o (bf16, reuses bufX)
  hipFuncSetAttribute(reinterpret_cast<const void*>(&attn_kernel),
                      hipFuncAttributeMaxDynamicSharedMemorySize, ATTN_LDS);
  attn_kernel<<<dim3(256 * 8), 256, ATTN_LDS, stream>>>(qkvQK, vtbuf, bufX);

  // 5) res2 = group_x + g_msa * (o @ W_out + b_out)  -> d_out (fp32)
  gemm128<2><<<dim3(ROWS_TOTAL / 128, 1024 / 128), 256, 0, stream>>>(
      bufX, wout_t, b_out, 1024, 1024, nullptr, out, group_x, ada, 2048);

  // 6) hmod
  rmsnorm_mod<<<ROWS_TOTAL, 256, 0, stream>>>(out, scale2, ada, 3072, 4096, bufX);

  // 7) h1 = gelu(hmod @ W_ff1 + b_ff1)
  gemm128<1><<<dim3(ROWS_TOTAL / 128, 4096 / 128), 256, 0, stream>>>(
      bufX, wff1_t, b_ff1, 1024, 4096, h1, nullptr, nullptr, nullptr, 0);

  // 8) d_out = res2 + g_mlp * (h1 @ W_ff2 + b_ff2)
  gemm128<3><<<dim3(ROWS_TOTAL / 128, 1024 / 128), 256, 0, stream>>>(
      h1, wff2_t, b_ff2, 4096, 1024, nullptr, out, nullptr, ada, 5120);
}

// Round 3
// 2083.214 us; speedup vs baseline: 1.1883x; 1.0143x over previous
//
#include <hip/hip_runtime.h>
#include <cstdint>
#include <cstddef>

typedef __bf16 bf16;
typedef __bf16 bf16x2 __attribute__((ext_vector_type(2)));
typedef __bf16 bf16x4 __attribute__((ext_vector_type(4)));
typedef __bf16 bf16x8 __attribute__((ext_vector_type(8)));
typedef float f32x4 __attribute__((ext_vector_type(4)));

#define D_MODEL 1024
#define ADA_STRIDE 6144
#define ROWS_TOTAL 32768   // 8 * 4096
#define EPS_RMS 1e-5f

// async global->LDS, 16B per lane; LDS dest must be wave-uniform base + lane*16
__device__ __forceinline__ void gld16(const void* g, void* l) {
  __builtin_amdgcn_global_load_lds((const __attribute__((address_space(1))) void*)g,
                                   (__attribute__((address_space(3))) void*)l, 16, 0, 0);
}

// ---------------------------------------------------------------------------
// Weight convert + transpose: Wt[n*K + k] = (bf16) W[k*N + n]
// ---------------------------------------------------------------------------
__global__ void wconvert_t(const float* __restrict__ W, bf16* __restrict__ Wt,
                           int kbits, int N, int total) {
  int i = blockIdx.x * 256 + threadIdx.x;
  if (i >= total) return;
  int K = 1 << kbits;
  int k = i & (K - 1);
  int n = i >> kbits;
  Wt[i] = (bf16)W[(size_t)k * N + n];
}

// ---------------------------------------------------------------------------
// ada = silu(context) @ W_ada + b_ada   (8 x 6144, K=1024)
// ---------------------------------------------------------------------------
__global__ void ada_gemm(const float* __restrict__ ctx, const float* __restrict__ W,
                         const float* __restrict__ bias, float* __restrict__ ada) {
  __shared__ float sc[D_MODEL];
  int b = blockIdx.y;
  int col = blockIdx.x * 256 + threadIdx.x;
  for (int j = threadIdx.x; j < D_MODEL; j += 256) {
    float x = ctx[b * D_MODEL + j];
    sc[j] = x / (1.f + __expf(-x));
  }
  __syncthreads();
  float acc = bias[col];
#pragma unroll 8
  for (int k = 0; k < D_MODEL; ++k)
    acc += sc[k] * W[(size_t)k * ADA_STRIDE + col];
  ada[b * ADA_STRIDE + col] = acc;
}

// ---------------------------------------------------------------------------
// Fused RMSNorm + adaLN modulation, fp32 in -> bf16 out.
// ---------------------------------------------------------------------------
__global__ void rmsnorm_mod(const float* __restrict__ x, const float* __restrict__ scale,
                            const float* __restrict__ ada, int shOff, int scOff,
                            bf16* __restrict__ out) {
  int row = blockIdx.x;
  int b = row >> 12;
  int t = threadIdx.x;
  const float* xr = x + (size_t)row * D_MODEL;
  float4 v = ((const float4*)xr)[t];
  float ss = v.x * v.x + v.y * v.y + v.z * v.z + v.w * v.w;
#pragma unroll
  for (int m = 32; m >= 1; m >>= 1) ss += __shfl_xor(ss, m, 64);
  __shared__ float ws[4];
  if ((t & 63) == 0) ws[t >> 6] = ss;
  __syncthreads();
  float tot = ws[0] + ws[1] + ws[2] + ws[3];
  float rms = rsqrtf(tot * (1.f / D_MODEL) + EPS_RMS);
  const float* ab = ada + b * ADA_STRIDE;
  int d0 = t * 4;
  float vv[4] = {v.x, v.y, v.z, v.w};
  bf16x4 o4;
#pragma unroll
  for (int j = 0; j < 4; ++j) {
    int d = d0 + j;
    float y = vv[j] * rms * scale[d];
    y = y * (1.f + ab[scOff + d]) + ab[shOff + d];
    o4[j] = (bf16)y;
  }
  *(bf16x4*)(out + (size_t)row * D_MODEL + d0) = o4;
}

// ---------------------------------------------------------------------------
// RoPE in place on qkvQK [32768][2048].
// ---------------------------------------------------------------------------
__global__ void rope_kernel(bf16* __restrict__ qk) {
  int gid = blockIdx.x * 256 + threadIdx.x;   // 32768 * 32
  int t = gid >> 5, i = gid & 31;
  int pos = t & 127;
  float fl = __expf((float)i * -0.14391156831f);   // 10000^(-i/64)
  float al = (float)pos * fl, ah = al * 0.01f;
  float sl, cl, sh, ch;
  __sincosf(al, &sl, &cl);
  __sincosf(ah, &sh, &ch);
  bf16* row = qk + (size_t)t * 2048;
  int d0 = i * 2;
#pragma unroll
  for (int h8 = 0; h8 < 16; ++h8) {
    bf16* hp = row + h8 * 128;
    bf16x2 lo = *(bf16x2*)(hp + d0);
    bf16x2 hi = *(bf16x2*)(hp + 64 + d0);
    bf16x2 olo, ohi;
#pragma unroll
    for (int j = 0; j < 2; ++j) {
      float xl = (float)lo[j], xh = (float)hi[j];
      olo[j] = (bf16)(xl * cl - xh * sl);
      ohi[j] = (bf16)(xh * ch + xl * sh);
    }
    *(bf16x2*)(hp + d0) = olo;
    *(bf16x2*)(hp + 64 + d0) = ohi;
  }
}

// ---------------------------------------------------------------------------
// MFMA bf16 GEMM, 128x128 tile, BK=64, global_load_lds, XOR-swizzled LDS.
// C[M,N] = A[M,K] @ Bt[N,K]^T + bias.
// LDS layout: row-major 64 bf16/row; 8-element group g of row r stored at
// physical group g^(r&7). Swizzle applied on global SOURCE addresses (gld16's
// LDS dest is fixed base+lane*16); within-row permutation keeps coalescing.
// MFMA operand order SWAPPED (first=B-frag, second=A-frag): C lane axis = M
// row, reg axis = 4 consecutive N cols -> vectorized bf16x4/float4 stores.
// EPI: 0 = bf16 (+bias[col]), 1 = gelu -> bf16, 2 = resid + g*(v), 3 = += g*v,
//      4 = bf16 (+bias[row]).
// ---------------------------------------------------------------------------
template <int EPI>
__global__ __launch_bounds__(256) void gemm128(
    const bf16* __restrict__ A, const bf16* __restrict__ Bt,
    const float* __restrict__ bias, int K, int N,
    bf16* __restrict__ outB, float* __restrict__ outF,
    const float* __restrict__ resid, const float* __restrict__ ada, int gOff) {
  __shared__ bf16 sA[128 * 64];
  __shared__ bf16 sB[128 * 64];
  const int tid = threadIdx.x;
  const int lane = tid & 63;
  const int wv = tid >> 6;
  const int wr = (wv >> 1) * 64;
  const int wc = (wv & 1) * 64;
  const int lm = lane & 15;
  const int quad = lane >> 4;
  const int tileM = blockIdx.x * 128;
  const int tileN = blockIdx.y * 128;
  // staging: chunk j (0..3): row = j*32 + (tid>>3); physical group pg = tid&7
  // logical source group = pg ^ (row&7) = pg ^ (sr&7)  (32 % 8 == 0)
  const int sr = tid >> 3;
  const int pg = tid & 7;
  const int xg = (pg ^ (sr & 7)) * 8;
  const bf16* gA = A + (size_t)(tileM + sr) * K + xg;
  const bf16* gB = Bt + (size_t)(tileN + sr) * K + xg;
  bf16* lA = sA + tid * 8;
  bf16* lB = sB + tid * 8;

  f32x4 acc[4][4];
#pragma unroll
  for (int i = 0; i < 4; ++i)
#pragma unroll
    for (int j = 0; j < 4; ++j) acc[i][j] = (f32x4){0.f, 0.f, 0.f, 0.f};

  for (int kk = 0; kk < K; kk += 64) {
    __syncthreads();
#pragma unroll
    for (int j = 0; j < 4; ++j) {
      gld16(gA + kk + (size_t)(j * 32) * K, lA + j * 2048);
      gld16(gB + kk + (size_t)(j * 32) * K, lB + j * 2048);
    }
    __syncthreads();
#pragma unroll
    for (int s = 0; s < 2; ++s) {
      bf16x8 af[4], bfr[4];
#pragma unroll
      for (int mi = 0; mi < 4; ++mi) {
        int row = wr + mi * 16 + lm;     // row&7 == lm&7
        af[mi] = *(const bf16x8*)(sA + row * 64 + ((s * 4 + quad) ^ (lm & 7)) * 8);
      }
#pragma unroll
      for (int ni = 0; ni < 4; ++ni) {
        int row = wc + ni * 16 + lm;
        bfr[ni] = *(const bf16x8*)(sB + row * 64 + ((s * 4 + quad) ^ (lm & 7)) * 8);
      }
#pragma unroll
      for (int mi = 0; mi < 4; ++mi)
#pragma unroll
        for (int ni = 0; ni < 4; ++ni)
          acc[mi][ni] = __builtin_amdgcn_mfma_f32_16x16x32_bf16(bfr[ni], af[mi], acc[mi][ni], 0, 0, 0);
  }
  }

  // epilogue: lane axis = M row, reg axis = 4 consecutive N cols
#pragma unroll
  for (int mi = 0; mi < 4; ++mi) {
    int grow = tileM + wr + mi * 16 + lm;
    int b = grow >> 12;
    float brow = (EPI == 4) ? bias[grow] : 0.f;
#pragma unroll
    for (int ni = 0; ni < 4; ++ni) {
      int col0 = tileN + wc + ni * 16 + quad * 4;
      size_t idx = (size_t)grow * N + col0;
      if (EPI == 0) {
        float4 b4 = *(const float4*)(bias + col0);
        float bb[4] = {b4.x, b4.y, b4.z, b4.w};
        bf16x4 o;
#pragma unroll
        for (int r = 0; r < 4; ++r) o[r] = (bf16)(acc[mi][ni][r] + bb[r]);
        *(bf16x4*)(outB + idx) = o;
      } else if (EPI == 4) {
        bf16x4 o;
#pragma unroll
        for (int r = 0; r < 4; ++r) o[r] = (bf16)(acc[mi][ni][r] + brow);
        *(bf16x4*)(outB + idx) = o;
      } else if (EPI == 1) {
        float4 b4 = *(const float4*)(bias + col0);
        float bb[4] = {b4.x, b4.y, b4.z, b4.w};
        bf16x4 o;
#pragma unroll
        for (int r = 0; r < 4; ++r) {
          float v = acc[mi][ni][r] + bb[r];
          // exact tanh-gelu via sigmoid: 0.5(1+tanh(s)) = sigmoid(2s)
          float s2 = 1.5957691216057308f * (v + 0.044715f * v * v * v);
          o[r] = (bf16)(v / (1.f + __expf(-s2)));
        }
        *(bf16x4*)(outB + idx) = o;
      } else if (EPI == 2) {
        float4 b4 = *(const float4*)(bias + col0);
        float4 g4 = *(const float4*)(ada + b * ADA_STRIDE + gOff + col0);
        float4 r4 = *(const float4*)(resid + idx);
        float4 o4;
        o4.x = r4.x + g4.x * (acc[mi][ni][0] + b4.x);
        o4.y = r4.y + g4.y * (acc[mi][ni][1] + b4.y);
        o4.z = r4.z + g4.z * (acc[mi][ni][2] + b4.z);
        o4.w = r4.w + g4.w * (acc[mi][ni][3] + b4.w);
        *(float4*)(outF + idx) = o4;
      } else {
        float4 b4 = *(const float4*)(bias + col0);
        float4 g4 = *(const float4*)(ada + b * ADA_STRIDE + gOff + col0);
        float4 r4 = *(const float4*)(outF + idx);
        float4 o4;
        o4.x = r4.x + g4.x * (acc[mi][ni][0] + b4.x);
        o4.y = r4.y + g4.y * (acc[mi][ni][1] + b4.y);
        o4.z = r4.z + g4.z * (acc[mi][ni][2] + b4.z);
        o4.w = r4.w + g4.w * (acc[mi][ni][3] + b4.w);
        *(float4*)(outF + idx) = o4;
      }
    }
  }
}

// ---------------------------------------------------------------------------
// MFMA windowed attention (unchanged from round 2).
// ---------------------------------------------------------------------------
#define ATTN_LDS 65536

__global__ __launch_bounds__(256, 2) void attn_kernel(
    const bf16* __restrict__ qk, const bf16* __restrict__ vt, bf16* __restrict__ o) {
  extern __shared__ char smem[];
  bf16* qbuf = (bf16*)smem;            // 128x128 swizzled (Q -> P)
  bf16* kbuf = qbuf + 128 * 128;       // 128x128 swizzled (K -> Vt)
  const int tid = threadIdx.x;
  const int lane = tid & 63;
  const int wv = tid >> 6;
  const int lm = lane & 15;
  const int quad = lane >> 4;
  const int w = blockIdx.x >> 3;
  const int h = blockIdx.x & 7;
  const int wbase = w * 128;

#pragma unroll
  for (int it = 0; it < 8; ++it) {
    int c = it * 256 + tid;
    int r = c >> 4, gst = c & 15;
    int goff = (gst ^ (r & 15)) * 8;
    const bf16* rowp = qk + (size_t)(wbase + r) * 2048 + h * 128 + goff;
    gld16(rowp, qbuf + c * 8);
    gld16(rowp + 1024, kbuf + c * 8);
  }
  __syncthreads();

  const int wq0 = wv * 32;
  f32x4 accS[8][2];
#pragma unroll
  for (int mi = 0; mi < 8; ++mi)
#pragma unroll
    for (int ni = 0; ni < 2; ++ni) accS[mi][ni] = (f32x4){0.f, 0.f, 0.f, 0.f};

#pragma unroll
  for (int s = 0; s < 4; ++s) {
    bf16x8 bq[2], ak[8];
#pragma unroll
    for (int ni = 0; ni < 2; ++ni)
      bq[ni] = *(const bf16x8*)(qbuf + (wq0 + ni * 16 + lm) * 128 + ((s * 4 + quad) ^ lm) * 8);
#pragma unroll
    for (int mi = 0; mi < 8; ++mi)
      ak[mi] = *(const bf16x8*)(kbuf + (mi * 16 + lm) * 128 + ((s * 4 + quad) ^ lm) * 8);
#pragma unroll
    for (int mi = 0; mi < 8; ++mi)
#pragma unroll
      for (int ni = 0; ni < 2; ++ni)
        accS[mi][ni] = __builtin_amdgcn_mfma_f32_16x16x32_bf16(ak[mi], bq[ni], accS[mi][ni], 0, 0, 0);
  }

  const float scl = 0.08838834764831845f;  // 1/sqrt(128)
  float mx[2] = {-1e30f, -1e30f}, sm[2] = {0.f, 0.f};
#pragma unroll
  for (int mi = 0; mi < 8; ++mi)
#pragma unroll
    for (int ni = 0; ni < 2; ++ni)
#pragma unroll
      for (int r = 0; r < 4; ++r) {
        accS[mi][ni][r] *= scl;
        mx[ni] = fmaxf(mx[ni], accS[mi][ni][r]);
      }
#pragma unroll
  for (int ni = 0; ni < 2; ++ni) {
    mx[ni] = fmaxf(mx[ni], __shfl_xor(mx[ni], 16, 64));
    mx[ni] = fmaxf(mx[ni], __shfl_xor(mx[ni], 32, 64));
  }
#pragma unroll
  for (int mi = 0; mi < 8; ++mi)
#pragma unroll
    for (int ni = 0; ni < 2; ++ni)
#pragma unroll
      for (int r = 0; r < 4; ++r) {
        accS[mi][ni][r] = __expf(accS[mi][ni][r] - mx[ni]);
        sm[ni] += accS[mi][ni][r];
      }
#pragma unroll
  for (int ni = 0; ni < 2; ++ni) {
    sm[ni] += __shfl_xor(sm[ni], 16, 64);
    sm[ni] += __shfl_xor(sm[ni], 32, 64);
    sm[ni] = 1.f / sm[ni];
  }
  __syncthreads();

#pragma unroll
  for (int mi = 0; mi < 8; ++mi)
#pragma unroll
    for (int ni = 0; ni < 2; ++ni) {
      int q = wq0 + ni * 16 + lm;
      int gst = (mi * 2 + (quad >> 1)) ^ lm;
      bf16x4 pk;
#pragma unroll
      for (int r = 0; r < 4; ++r) pk[r] = (bf16)(accS[mi][ni][r] * sm[ni]);
      *(bf16x4*)(qbuf + q * 128 + gst * 8 + (quad & 1) * 4) = pk;
    }
#pragma unroll
  for (int it = 0; it < 8; ++it) {
    int c = it * 256 + tid;
    int r = c >> 4, gst = c & 15;
    gld16(vt + (size_t)(h * 128 + r) * 32768 + wbase + (gst ^ (r & 15)) * 8, kbuf + c * 8);
  }
  __syncthreads();

  f32x4 accO[2][8];
#pragma unroll
  for (int mi = 0; mi < 2; ++mi)
#pragma unroll
    for (int ni = 0; ni < 8; ++ni) accO[mi][ni] = (f32x4){0.f, 0.f, 0.f, 0.f};
#pragma unroll
  for (int s = 0; s < 4; ++s) {
    bf16x8 ap[2], bv[8];
#pragma unroll
    for (int mi = 0; mi < 2; ++mi)
      ap[mi] = *(const bf16x8*)(qbuf + (wq0 + mi * 16 + lm) * 128 + ((s * 4 + quad) ^ lm) * 8);
#pragma unroll
    for (int ni = 0; ni < 8; ++ni)
      bv[ni] = *(const bf16x8*)(kbuf + (ni * 16 + lm) * 128 + ((s * 4 + quad) ^ lm) * 8);
#pragma unroll
    for (int mi = 0; mi < 2; ++mi)
#pragma unroll
      for (int ni = 0; ni < 8; ++ni)
        accO[mi][ni] = __builtin_amdgcn_mfma_f32_16x16x32_bf16(ap[mi], bv[ni], accO[mi][ni], 0, 0, 0);
  }

#pragma unroll
  for (int mi = 0; mi < 2; ++mi)
#pragma unroll
    for (int ni = 0; ni < 8; ++ni) {
      int d = ni * 16 + lm;
#pragma unroll
      for (int r = 0; r < 4; ++r) {
        int q = wq0 + mi * 16 + quad * 4 + r;
        o[(size_t)(wbase + q) * 1024 + h * 128 + d] = (bf16)accO[mi][ni][r];
      }
    }
}

// ---------------------------------------------------------------------------
extern "C" void kernel_launch(void* const* d_in, const int* in_sizes, int n_in,
                              void* d_out, int out_size, void* d_ws, size_t ws_size,
                              hipStream_t stream) {
  const float* group_x = (const float*)d_in[0];
  const float* context = (const float*)d_in[1];
  const float* W_ada   = (const float*)d_in[2];
  const float* b_ada   = (const float*)d_in[3];
  const float* scale1  = (const float*)d_in[4];
  const float* W_qkv   = (const float*)d_in[5];
  const float* b_qkv   = (const float*)d_in[6];
  const float* W_out   = (const float*)d_in[7];
  const float* b_out   = (const float*)d_in[8];
  const float* scale2  = (const float*)d_in[9];
  const float* W_ff1   = (const float*)d_in[10];
  const float* b_ff1   = (const float*)d_in[11];
  const float* W_ff2   = (const float*)d_in[12];
  const float* b_ff2   = (const float*)d_in[13];
  float* out = (float*)d_out;

  char* ws = (char*)d_ws;
  float* ada   = (float*)ws;                          // 196,608 B
  bf16* wqkv_t = (bf16*)(ws + 196608);                // 3072x1024 (rows 2048.. are Wv^T)
  bf16* wout_t = wqkv_t + (size_t)3072 * 1024;        // 1024x1024
  bf16* wff1_t = wout_t + (size_t)1024 * 1024;        // 4096x1024
  bf16* wff2_t = wff1_t + (size_t)4096 * 1024;        // 1024x4096
  bf16* bufX   = wff2_t + (size_t)1024 * 4096;        // 32768x1024 (xmod -> o -> hmod)
  bf16* qkvQK  = bufX + (size_t)ROWS_TOTAL * 1024;    // 32768x2048 (roped in place)
  bf16* vtbuf  = qkvQK + (size_t)ROWS_TOTAL * 2048;   // 1024x32768
  bf16* h1     = qkvQK;                               // 32768x4096 aliases qkvQK+vtbuf

  // 0) weight convert+transpose
  wconvert_t<<<dim3(3072 * 1024 / 256), 256, 0, stream>>>(W_qkv, wqkv_t, 10, 3072, 3072 * 1024);
  wconvert_t<<<dim3(1024 * 1024 / 256), 256, 0, stream>>>(W_out, wout_t, 10, 1024, 1024 * 1024);
  wconvert_t<<<dim3(4096 * 1024 / 256), 256, 0, stream>>>(W_ff1, wff1_t, 10, 4096, 4096 * 1024);
  wconvert_t<<<dim3(1024 * 4096 / 256), 256, 0, stream>>>(W_ff2, wff2_t, 12, 1024, 1024 * 4096);

  // 1) ada
  ada_gemm<<<dim3(ADA_STRIDE / 256, 8), 256, 0, stream>>>(context, W_ada, b_ada, ada);

  // 2) xmod
  rmsnorm_mod<<<ROWS_TOTAL, 256, 0, stream>>>(group_x, scale1, ada, 0, 1024, bufX);

  // 3a) qk = xmod @ W_qk + b   (N=2048)
  gemm128<0><<<dim3(ROWS_TOTAL / 128, 2048 / 128), 256, 0, stream>>>(
      bufX, wqkv_t, b_qkv, 1024, 2048, qkvQK, nullptr, nullptr, nullptr, 0);

  // 3b) vT[vfeat][token] = Wv^T @ xmod^T + b_v[row]  (M=1024, N=32768)
  gemm128<4><<<dim3(1024 / 128, ROWS_TOTAL / 128), 256, 0, stream>>>(
      wqkv_t + (size_t)2048 * 1024, bufX, b_qkv + 2048, 1024, ROWS_TOTAL,
      vtbuf, nullptr, nullptr, nullptr, 0);

  // 3c) rope q,k in place
  rope_kernel<<<dim3(ROWS_TOTAL * 32 / 256), 256, 0, stream>>>(qkvQK);

  // 4) attention -> o (bf16, reuses bufX)
  hipFuncSetAttribute(reinterpret_cast<const void*>(&attn_kernel),
                      hipFuncAttributeMaxDynamicSharedMemorySize, ATTN_LDS);
  attn_kernel<<<dim3(256 * 8), 256, ATTN_LDS, stream>>>(qkvQK, vtbuf, bufX);

  // 5) res2 = group_x + g_msa * (o @ W_out + b_out)  -> d_out (fp32)
  gemm128<2><<<dim3(ROWS_TOTAL / 128, 1024 / 128), 256, 0, stream>>>(
      bufX, wout_t, b_out, 1024, 1024, nullptr, out, group_x, ada, 2048);

  // 6) hmod
  rmsnorm_mod<<<ROWS_TOTAL, 256, 0, stream>>>(out, scale2, ada, 3072, 4096, bufX);

  // 7) h1 = gelu(hmod @ W_ff1 + b_ff1)
  gemm128<1><<<dim3(ROWS_TOTAL / 128, 4096 / 128), 256, 0, stream>>>(
      bufX, wff1_t, b_ff1, 1024, 4096, h1, nullptr, nullptr, nullptr, 0);

  // 8) d_out = res2 + g_mlp * (h1 @ W_ff2 + b_ff2)
  gemm128<3><<<dim3(ROWS_TOTAL / 128, 1024 / 128), 256, 0, stream>>>(
      h1, wff2_t, b_ff2, 4096, 1024, nullptr, out, nullptr, ada, 5120);
}